// Round 1
// baseline (1243.933 us; speedup 1.0000x reference)
//
#include <hip/hip_runtime.h>

// Monarch matrix: out = P(R_bdmm(P(L_bdmm(P(x))))) + bias, S=128, n=16384.
// Folded form:
//   Y[t][p][q]      = sum_k L[p,q,k] * x[t, k*128+p]          (stage A)
//   out[t,i*128+j]  = sum_m R[j,i,m] * Y[t][m][j] + bias[...] (stage B)
// Y lives in d_out (stage B reads exactly the region it overwrites; per-block
// exclusive address sets -> race-free, no workspace dependence).

#define NFEAT 16384
#define SDIM  128

// Relaid weights: Lr[m][k][j] = L[m][j][k] ; Rr[j][m][i] = R[j][i][m].
// 8 MB each as static device globals (no hipMalloc allowed in kernel_launch).
__device__ float g_Lr[SDIM * SDIM * SDIM];
__device__ float g_Rr[SDIM * SDIM * SDIM];

__global__ __launch_bounds__(512, 2) void relayout_kernel(
    const float* __restrict__ L, const float* __restrict__ R) {
  unsigned idx = blockIdx.x * 512u + threadIdx.x;  // 0 .. 2^21-1
  unsigned a = idx >> 14;          // m (for L) / j (for R)
  unsigned b = (idx >> 7) & 127u;  // k (for L) / m (for R)
  unsigned c = idx & 127u;         // j (for L) / i (for R)
  // both relayouts are "swap last two dims": src = [a][c][b]
  g_Lr[idx] = L[(a << 14) + (c << 7) + b];
  g_Rr[idx] = R[(a << 14) + (c << 7) + b];
}

// ---------------- Stage A ----------------
// block = 512 threads, tile: 8 t-rows x 32 m-cols (chunk mc) x all 128 j.
// thread: m_l = tid>>4 (0..31), j0 = (tid&15)*8 -> acc[8t][8j].
// LDS slab xs[k-local 8][m-local 32][t 8 pad->12], double buffered.
__global__ __launch_bounds__(512, 4) void stageA_kernel(
    const float* __restrict__ x, float* __restrict__ Y) {
  __shared__ float xs[2][8 * 32 * 12];

  const int tid = threadIdx.x;
  const int bx  = blockIdx.x;
  // XCD pinning: round-robin bx%8 -> XCD; give each XCD a fixed m-chunk so its
  // 2 MB weight slice stays L2-resident.  Bijective for grid % 8 == 0.
  const int xcd = bx & 7;
  const int mc  = xcd & 3;                         // m-chunk 0..3
  const int tt  = ((bx >> 3) << 1) | (xcd >> 2);   // t-tile 0..511
  const int t0  = tt << 3;

  const int m_l  = tid >> 4;              // 0..31
  const int mcol = (mc << 5) + m_l;       // 0..127
  const int j0   = (tid & 15) << 3;       // 0..120

  // staging role
  const int s_m  = tid & 31;
  const int s_k  = (tid >> 5) & 7;
  const int s_th = tid >> 8;              // 0..1 -> t-quad

  float acc[8][8];
#pragma unroll
  for (int t = 0; t < 8; ++t)
#pragma unroll
    for (int j = 0; j < 8; ++j) acc[t][j] = 0.f;

  const float* xsrc = x + (size_t)(t0 + (s_th << 2)) * NFEAT + (mc << 5) + s_m;
  const float* wrow = g_Lr + ((size_t)mcol << 14) + j0;  // + k*128 per step
  const int sidx = ((s_k << 5) + s_m) * 12 + (s_th << 2);

  // prologue: stage kc=0 into buf 0
  {
    const float* s = xsrc + (size_t)s_k * SDIM;
    float4 v;
    v.x = s[0]; v.y = s[NFEAT]; v.z = s[2 * NFEAT]; v.w = s[3 * NFEAT];
    *(float4*)&xs[0][sidx] = v;
  }

  for (int kc = 0; kc < 16; ++kc) {
    __syncthreads();  // buf[kc&1] ready; buf[(kc+1)&1] free (reads done last iter)
    float4 vn;
    if (kc < 15) {  // issue next-chunk loads early; latency hides under FMAs
      const float* s = xsrc + (size_t)(((kc + 1) << 3) + s_k) * SDIM;
      vn.x = s[0]; vn.y = s[NFEAT]; vn.z = s[2 * NFEAT]; vn.w = s[3 * NFEAT];
    }
    const float* xb = &xs[kc & 1][0];
#pragma unroll
    for (int kk = 0; kk < 8; ++kk) {
      const int k = (kc << 3) + kk;
      const float4 xa = *(const float4*)&xb[((kk << 5) + m_l) * 12 + 0];
      const float4 xc = *(const float4*)&xb[((kk << 5) + m_l) * 12 + 4];
      const float4 wa = *(const float4*)&wrow[(size_t)k << 7];
      const float4 wb = *(const float4*)&wrow[((size_t)k << 7) + 4];
      const float xv[8] = {xa.x, xa.y, xa.z, xa.w, xc.x, xc.y, xc.z, xc.w};
      const float wv[8] = {wa.x, wa.y, wa.z, wa.w, wb.x, wb.y, wb.z, wb.w};
#pragma unroll
      for (int t = 0; t < 8; ++t)
#pragma unroll
        for (int j = 0; j < 8; ++j) acc[t][j] = fmaf(xv[t], wv[j], acc[t][j]);
    }
    if (kc < 15) *(float4*)&xs[(kc + 1) & 1][sidx] = vn;
  }

  // write Y[t0+t][mcol][j0..j0+7] (32B runs, coalesced across j-groups)
  float* yrow = Y + ((size_t)mcol << 7) + j0;
#pragma unroll
  for (int t = 0; t < 8; ++t) {
    float4 o0 = {acc[t][0], acc[t][1], acc[t][2], acc[t][3]};
    float4 o1 = {acc[t][4], acc[t][5], acc[t][6], acc[t][7]};
    float* p = yrow + (size_t)(t0 + t) * NFEAT;
    *(float4*)p = o0;
    *(float4*)(p + 4) = o1;
  }
}

// ---------------- Stage B ----------------
// Mirror of stage A: contraction over m, lane dim = j (32-col chunk jc),
// out groups of 8 i per thread.  Reads Y from `buf`(=d_out), overwrites same
// region at the end.
__global__ __launch_bounds__(512, 4) void stageB_kernel(
    const float* __restrict__ bias, float* buf) {
  __shared__ float ys[2][8 * 32 * 12];

  const int tid = threadIdx.x;
  const int bx  = blockIdx.x;
  const int xcd = bx & 7;
  const int jc  = xcd & 3;
  const int tt  = ((bx >> 3) << 1) | (xcd >> 2);
  const int t0  = tt << 3;

  const int jl   = tid & 31;
  const int jcol = (jc << 5) + jl;
  const int i0   = (tid >> 5) << 3;  // 0..120

  const int s_j  = tid & 31;
  const int s_mu = (tid >> 5) & 7;
  const int s_th = tid >> 8;

  float acc[8][8];
#pragma unroll
  for (int t = 0; t < 8; ++t)
#pragma unroll
    for (int i = 0; i < 8; ++i) acc[t][i] = 0.f;

  const float* ysrc = buf + (size_t)(t0 + (s_th << 2)) * NFEAT + (jc << 5) + s_j;
  const float* wrow = g_Rr + ((size_t)jcol << 14) + i0;  // + m*128 per step
  const int sidx = ((s_mu << 5) + s_j) * 12 + (s_th << 2);

  {
    const float* s = ysrc + (size_t)s_mu * SDIM;
    float4 v;
    v.x = s[0]; v.y = s[NFEAT]; v.z = s[2 * NFEAT]; v.w = s[3 * NFEAT];
    *(float4*)&ys[0][sidx] = v;
  }

  for (int mcc = 0; mcc < 16; ++mcc) {
    __syncthreads();
    float4 vn;
    if (mcc < 15) {
      const float* s = ysrc + (size_t)(((mcc + 1) << 3) + s_mu) * SDIM;
      vn.x = s[0]; vn.y = s[NFEAT]; vn.z = s[2 * NFEAT]; vn.w = s[3 * NFEAT];
    }
    const float* yb = &ys[mcc & 1][0];
#pragma unroll
    for (int mm = 0; mm < 8; ++mm) {
      const int m = (mcc << 3) + mm;
      const float4 ya = *(const float4*)&yb[((mm << 5) + jl) * 12 + 0];
      const float4 yc = *(const float4*)&yb[((mm << 5) + jl) * 12 + 4];
      const float4 wa = *(const float4*)&wrow[(size_t)m << 7];
      const float4 wb = *(const float4*)&wrow[((size_t)m << 7) + 4];
      const float yv[8] = {ya.x, ya.y, ya.z, ya.w, yc.x, yc.y, yc.z, yc.w};
      const float wv[8] = {wa.x, wa.y, wa.z, wa.w, wb.x, wb.y, wb.z, wb.w};
#pragma unroll
      for (int t = 0; t < 8; ++t)
#pragma unroll
        for (int i = 0; i < 8; ++i) acc[t][i] = fmaf(yv[t], wv[i], acc[t][i]);
    }
    if (mcc < 15) *(float4*)&ys[(mcc + 1) & 1][sidx] = vn;
  }

  // epilogue: out[t0+t][(i0+ii)*128 + jcol] = acc + bias  (lane-coalesced over jl)
#pragma unroll
  for (int ii = 0; ii < 8; ++ii) {
    const float b = bias[((i0 + ii) << 7) + jcol];
#pragma unroll
    for (int t = 0; t < 8; ++t) {
      buf[(size_t)(t0 + t) * NFEAT + ((i0 + ii) << 7) + jcol] = acc[t][ii] + b;
    }
  }
}

extern "C" void kernel_launch(void* const* d_in, const int* in_sizes, int n_in,
                              void* d_out, int out_size, void* d_ws, size_t ws_size,
                              hipStream_t stream) {
  const float* x    = (const float*)d_in[0];
  const float* L    = (const float*)d_in[1];
  const float* R    = (const float*)d_in[2];
  const float* bias = (const float*)d_in[3];
  float* out = (float*)d_out;

  const int rows = in_sizes[0] / NFEAT;   // 4096
  const int nblk = (rows / 8) * 4;        // 2048 (multiple of 8 for XCD decode)

  relayout_kernel<<<(SDIM * SDIM * SDIM) / 512, 512, 0, stream>>>(L, R);
  stageA_kernel<<<nblk, 512, 0, stream>>>(x, out);
  stageB_kernel<<<nblk, 512, 0, stream>>>(bias, out);
}